// Round 2
// baseline (614.216 us; speedup 1.0000x reference)
//
#include <hip/hip_runtime.h>
#include <hip/hip_bf16.h>

// GCN (2-layer, PyG-style symmetric norm + self loops) + edge MLP.
// Strategy:
//  - Build CSR grouped by dst once per call (hist -> scan -> fill). No fp32 atomics.
//  - gcn_conv as: t = h@W (dense, per-node), then gather-aggregate per node:
//      out[v] = relu(dinv[v]*( t[v]*dinv[v] + sum_{(s,v)} t[s]*dinv[s] ) + b)
//  - Edge MLP: ef@Wm1 = A[src]+B[dst] where A=h2@Wm1[:H], B=h2@Wm1[H:], precomputed
//    per node (moves the 14.7 GFLOP per-edge GEMM to 0.8 GFLOP per-node).
//    Per edge only: relu(A[s]+B[d]+bm1) @ Wm2 + bm2 (1024 FMA/edge).

#define HDIM 64
#define CDIM 16

static inline int ceil_div(int a, int b){ return (a+b-1)/b; }

__global__ void k_zero_i32(int* p, int n){
  int i = blockIdx.x*blockDim.x + threadIdx.x;
  if(i<n) p[i]=0;
}

__global__ void k_hist(const int* __restrict__ dst, int* __restrict__ cnt, int E){
  int e = blockIdx.x*blockDim.x + threadIdx.x;
  if(e<E) atomicAdd(&cnt[dst[e]], 1);
}

__global__ void k_dinv(const int* __restrict__ cnt, float* __restrict__ dinv, int N){
  int i = blockIdx.x*blockDim.x + threadIdx.x;
  if(i<N) dinv[i] = 1.0f / sqrtf(1.0f + (float)cnt[i]);  // deg = in_deg + self loop >= 1
}

// Single-block scan: each thread serially sums a contiguous chunk, block-ladder
// scans the 1024 partials, then each thread writes its chunk's running prefix.
__global__ __launch_bounds__(1024) void k_scan(const int* __restrict__ cnt,
                                               int* __restrict__ row_start,
                                               int* __restrict__ cursor, int N){
  const int T=1024;
  __shared__ int tmp[T];
  int tid = threadIdx.x;
  int chunk = (N+T-1)/T;
  int lo = tid*chunk;
  int hi = lo+chunk; if(hi>N) hi=N;
  int s=0;
  for(int i=lo;i<hi;i++) s += cnt[i];
  tmp[tid]=s; __syncthreads();
  for(int off=1;off<T;off<<=1){
    int add = (tid>=off)? tmp[tid-off] : 0;
    __syncthreads();
    tmp[tid] += add;
    __syncthreads();
  }
  int run = tmp[tid]-s;  // exclusive prefix of this thread's chunk
  for(int i=lo;i<hi;i++){
    row_start[i]=run; cursor[i]=run; run += cnt[i];
  }
}

__global__ void k_fill(const int* __restrict__ src, const int* __restrict__ dst,
                       const float* __restrict__ dinv, int* __restrict__ cursor,
                       int* __restrict__ csr_src, float* __restrict__ csr_w, int E){
  int e = blockIdx.x*blockDim.x + threadIdx.x;
  if(e>=E) return;
  int s = src[e], d = dst[e];
  int pos = atomicAdd(&cursor[d], 1);
  csr_src[pos] = s;
  csr_w[pos]   = dinv[s];
}

// out[n][c] = sum_k in[n][k] * W[k][c]; one block = 256/COLS nodes,
// input rows staged in LDS (broadcast reads), W reads coalesced + L1-resident.
template<int K, int COLS>
__global__ __launch_bounds__(256) void k_gemm(const float* __restrict__ in,
                                              const float* __restrict__ W,
                                              float* __restrict__ out, int N){
  const int NODES = 256/COLS;
  __shared__ float srow[NODES*K];
  int n0 = blockIdx.x*NODES;
  for(int i=threadIdx.x; i<NODES*K; i+=256){
    int g = n0*K + i;
    srow[i] = (g < N*K) ? in[g] : 0.f;
  }
  __syncthreads();
  int c = threadIdx.x % COLS;
  int y = threadIdx.x / COLS;
  int n = n0+y;
  if(n>=N) return;
  float acc=0.f;
  #pragma unroll
  for(int k=0;k<K;k++) acc += srow[y*K+k]*W[k*COLS+c];
  out[n*COLS+c]=acc;
}

// AB[n][0..63] = h2[n] @ Wm1[0:64,:]; AB[n][64..127] = h2[n] @ Wm1[64:128,:]
__global__ __launch_bounds__(256) void k_gemm3(const float* __restrict__ h2,
                                               const float* __restrict__ Wm1,
                                               float* __restrict__ AB, int N){
  __shared__ float srow[2*HDIM];
  int n0 = blockIdx.x*2;
  for(int i=threadIdx.x; i<2*HDIM; i+=256){
    int g = n0*HDIM + i;
    srow[i] = (g < N*HDIM) ? h2[g] : 0.f;
  }
  __syncthreads();
  int c = threadIdx.x & 127;
  int y = threadIdx.x >> 7;
  int n = n0+y;
  if(n>=N) return;
  const float* Wcol = (c < HDIM) ? (Wm1 + c) : (Wm1 + HDIM*HDIM + (c-HDIM));
  float acc=0.f;
  #pragma unroll
  for(int k=0;k<HDIM;k++) acc += srow[y*HDIM+k]*Wcol[k*HDIM];
  AB[n*128+c]=acc;
}

// One wave per node v, lane = feature c. Gather-side aggregation over CSR row.
// 2-way unrolled so two neighbor gathers are in flight per iteration.
__global__ __launch_bounds__(256) void k_agg(const float* __restrict__ t,
                                             const int* __restrict__ csr_src,
                                             const float* __restrict__ csr_w,
                                             const int* __restrict__ row_start,
                                             const int* __restrict__ cnt,
                                             const float* __restrict__ dinv,
                                             const float* __restrict__ bias,
                                             float* __restrict__ out, int N){
  int c = threadIdx.x & 63;
  int v = blockIdx.x*4 + (threadIdx.x>>6);
  if(v>=N) return;
  float dv = dinv[v];
  float acc = t[(size_t)v*HDIM+c]*dv;   // self-loop term (x dv again at the end)
  int j0 = row_start[v];
  int j1 = j0 + cnt[v];
  int j = j0;
  for(; j+1<j1; j+=2){
    int   s0 = csr_src[j],   s1 = csr_src[j+1];
    float w0 = csr_w[j],     w1 = csr_w[j+1];
    float t0 = t[(size_t)s0*HDIM+c];
    float t1 = t[(size_t)s1*HDIM+c];
    acc += t0*w0;
    acc += t1*w1;
  }
  if(j<j1){
    int s = csr_src[j];
    acc += t[(size_t)s*HDIM+c]*csr_w[j];
  }
  float r = acc*dv + bias[c];
  out[(size_t)v*HDIM+c] = r>0.f ? r : 0.f;
}

// One thread per edge: acc[c] = bm2[c] + sum_k relu(A[s][k]+B[d][k]+bm1[k])*Wm2[k][c]
__global__ __launch_bounds__(256) void k_edge_mlp(const int* __restrict__ src,
                                                  const int* __restrict__ dst,
                                                  const float* __restrict__ AB,
                                                  const float* __restrict__ bm1,
                                                  const float* __restrict__ Wm2,
                                                  const float* __restrict__ bm2,
                                                  float* __restrict__ out, int E){
  int e = blockIdx.x*blockDim.x + threadIdx.x;
  if(e>=E) return;
  int s = src[e], d = dst[e];
  const float4* Af = (const float4*)(AB + (size_t)s*128);
  const float4* Bf = (const float4*)(AB + (size_t)d*128 + 64);
  const float4* bm1f = (const float4*)bm1;
  const float4* bm2f = (const float4*)bm2;
  float acc[CDIM];
  {
    float4 c0 = bm2f[0], c1 = bm2f[1], c2 = bm2f[2], c3 = bm2f[3];
    acc[0]=c0.x; acc[1]=c0.y; acc[2]=c0.z; acc[3]=c0.w;
    acc[4]=c1.x; acc[5]=c1.y; acc[6]=c1.z; acc[7]=c1.w;
    acc[8]=c2.x; acc[9]=c2.y; acc[10]=c2.z; acc[11]=c2.w;
    acc[12]=c3.x; acc[13]=c3.y; acc[14]=c3.z; acc[15]=c3.w;
  }
  #pragma unroll
  for(int k0=0;k0<16;k0++){
    float4 a = Af[k0];
    float4 b = Bf[k0];
    float4 bb = bm1f[k0];   // wave-uniform -> s_load
    float z0 = a.x+b.x+bb.x; z0 = z0>0.f? z0:0.f;
    float z1 = a.y+b.y+bb.y; z1 = z1>0.f? z1:0.f;
    float z2 = a.z+b.z+bb.z; z2 = z2>0.f? z2:0.f;
    float z3 = a.w+b.w+bb.w; z3 = z3>0.f? z3:0.f;
    #pragma unroll
    for(int c=0;c<CDIM;c++){
      acc[c] += z0 * Wm2[(k0*4+0)*CDIM + c];
      acc[c] += z1 * Wm2[(k0*4+1)*CDIM + c];
      acc[c] += z2 * Wm2[(k0*4+2)*CDIM + c];
      acc[c] += z3 * Wm2[(k0*4+3)*CDIM + c];
    }
  }
  float4* o = (float4*)(out + (size_t)e*CDIM);
  o[0] = make_float4(acc[0],acc[1],acc[2],acc[3]);
  o[1] = make_float4(acc[4],acc[5],acc[6],acc[7]);
  o[2] = make_float4(acc[8],acc[9],acc[10],acc[11]);
  o[3] = make_float4(acc[12],acc[13],acc[14],acc[15]);
}

extern "C" void kernel_launch(void* const* d_in, const int* in_sizes, int n_in,
                              void* d_out, int out_size, void* d_ws, size_t ws_size,
                              hipStream_t stream) {
  const float* x   = (const float*)d_in[0];
  const int*   ei  = (const int*)  d_in[1];
  const float* W1  = (const float*)d_in[2];
  const float* b1  = (const float*)d_in[3];
  const float* W2  = (const float*)d_in[4];
  const float* b2  = (const float*)d_in[5];
  const float* Wm1 = (const float*)d_in[6];
  const float* bm1 = (const float*)d_in[7];
  const float* Wm2 = (const float*)d_in[8];
  const float* bm2 = (const float*)d_in[9];
  float* out = (float*)d_out;

  const int N = in_sizes[0]/128;
  const int E = in_sizes[1]/2;
  const int* src = ei;
  const int* dst = ei + E;

  // ws layout (256B-aligned). AB (25.6MB) aliases tbuf's region: tbuf is dead
  // by the time k_gemm3 writes AB, and hbuf (gemm3's input) sits after AB.
  char* ws = (char*)d_ws;
  size_t off = 0;
  auto alloc = [&](size_t bytes)->char*{
    char* p = ws + off; off += (bytes + 255) & ~(size_t)255; return p;
  };
  int*   cnt       = (int*)  alloc((size_t)N*4);
  int*   row_start = (int*)  alloc((size_t)N*4);
  int*   cursor    = (int*)  alloc((size_t)N*4);
  float* dinv      = (float*)alloc((size_t)N*4);
  int*   csr_src   = (int*)  alloc((size_t)E*4);
  float* csr_w     = (float*)alloc((size_t)E*4);
  float* AB        = (float*)alloc((size_t)N*128*4);  // also hosts tbuf in its low half
  float* tbuf      = AB;
  float* hbuf      = (float*)alloc((size_t)N*64*4);

  // --- CSR build ---
  k_zero_i32<<<ceil_div(N,256),256,0,stream>>>(cnt, N);
  k_hist    <<<ceil_div(E,256),256,0,stream>>>(dst, cnt, E);
  k_dinv    <<<ceil_div(N,256),256,0,stream>>>(cnt, dinv, N);
  k_scan    <<<1,1024,0,stream>>>(cnt, row_start, cursor, N);
  k_fill    <<<ceil_div(E,256),256,0,stream>>>(src, dst, dinv, cursor, csr_src, csr_w, E);

  // --- layer 1 ---  (NODES per block = 256/COLS)
  k_gemm<128,64><<<ceil_div(N,256/64),256,0,stream>>>(x, W1, tbuf, N);
  k_agg        <<<ceil_div(N,4),256,0,stream>>>(tbuf, csr_src, csr_w, row_start, cnt,
                                                dinv, b1, hbuf, N);
  // --- layer 2 ---
  k_gemm<64,64><<<ceil_div(N,256/64),256,0,stream>>>(hbuf, W2, tbuf, N);
  k_agg        <<<ceil_div(N,4),256,0,stream>>>(tbuf, csr_src, csr_w, row_start, cnt,
                                                dinv, b2, hbuf, N);
  // --- edge MLP ---
  k_gemm3   <<<ceil_div(N,2),256,0,stream>>>(hbuf, Wm1, AB, N);
  k_edge_mlp<<<ceil_div(E,256),256,0,stream>>>(src, dst, AB, bm1, Wm2, bm2, out, E);
}

// Round 3
// 516.207 us; speedup vs baseline: 1.1899x; 1.1899x over previous
//
#include <hip/hip_runtime.h>
#include <hip/hip_bf16.h>

// GCN (2-layer, PyG-style symmetric norm + self loops) + edge MLP.
// Strategy:
//  - Build CSR grouped by dst once per call (hist -> 3-level scan -> fill).
//  - gcn_conv as: t = h@W (dense, per-node), then gather-aggregate per node:
//      out[v] = relu(dinv[v]*( t[v]*dinv[v] + sum_{(s,v)} t[s]*dinv[s] ) + b)
//  - Edge MLP: ef@Wm1 = A[src]+B[dst] where A=h2@Wm1[:H], B=h2@Wm1[H:], precomputed
//    per node (moves the 14.7 GFLOP per-edge GEMM to 0.8 GFLOP per-node).
//    Per edge only: relu(A[s]+B[d]+bm1) @ Wm2 + bm2 (1024 FMA/edge).
// R2: replaced single-block k_scan (111us, 0.14% occupancy) with 3-level
//     decoupled scan (blocksum -> scan partials -> write prefix), dinv fused.

#define HDIM 64
#define CDIM 16

static inline int ceil_div(int a, int b){ return (a+b-1)/b; }

__global__ void k_zero_i32(int* p, int n){
  int i = blockIdx.x*blockDim.x + threadIdx.x;
  if(i<n) p[i]=0;
}

__global__ void k_hist(const int* __restrict__ dst, int* __restrict__ cnt, int E){
  int e = blockIdx.x*blockDim.x + threadIdx.x;
  if(e<E) atomicAdd(&cnt[dst[e]], 1);
}

// Level 1: per-block (256 nodes) sum of cnt -> bsum[block]
__global__ __launch_bounds__(256) void k_blocksum(const int* __restrict__ cnt,
                                                  int* __restrict__ bsum, int N){
  __shared__ int part[4];
  int i = blockIdx.x*256 + threadIdx.x;
  int v = (i<N) ? cnt[i] : 0;
  #pragma unroll
  for(int off=32; off>0; off>>=1) v += __shfl_down(v, off, 64);
  if((threadIdx.x & 63)==0) part[threadIdx.x>>6] = v;
  __syncthreads();
  if(threadIdx.x==0) bsum[blockIdx.x] = part[0]+part[1]+part[2]+part[3];
}

// Level 2: one block scans the per-block sums (nb <= 1024) -> exclusive prefix.
__global__ __launch_bounds__(1024) void k_scan_bsums(int* __restrict__ bsum, int nb){
  __shared__ int tmp[1024];
  int tid = threadIdx.x;
  int v = (tid<nb) ? bsum[tid] : 0;
  tmp[tid] = v; __syncthreads();
  for(int off=1; off<1024; off<<=1){
    int add = (tid>=off) ? tmp[tid-off] : 0;
    __syncthreads();
    tmp[tid] += add;
    __syncthreads();
  }
  if(tid<nb) bsum[tid] = tmp[tid] - v;   // exclusive
}

// Level 3: in-block exclusive scan of cnt + block offset -> row_start/cursor.
// Also computes dinv (needs only cnt) to save a launch.
__global__ __launch_bounds__(256) void k_write_prefix(const int* __restrict__ cnt,
                                                      const int* __restrict__ bsum,
                                                      int* __restrict__ row_start,
                                                      int* __restrict__ cursor,
                                                      float* __restrict__ dinv, int N){
  __shared__ int tmp[256];
  int tid = threadIdx.x;
  int i = blockIdx.x*256 + tid;
  int v = (i<N) ? cnt[i] : 0;
  tmp[tid] = v; __syncthreads();
  for(int off=1; off<256; off<<=1){
    int add = (tid>=off) ? tmp[tid-off] : 0;
    __syncthreads();
    tmp[tid] += add;
    __syncthreads();
  }
  if(i<N){
    int ex = bsum[blockIdx.x] + tmp[tid] - v;
    row_start[i] = ex;
    cursor[i]    = ex;
    dinv[i]      = 1.0f / sqrtf(1.0f + (float)v);  // deg >= 1 via self-loop
  }
}

__global__ void k_fill(const int* __restrict__ src, const int* __restrict__ dst,
                       const float* __restrict__ dinv, int* __restrict__ cursor,
                       int* __restrict__ csr_src, float* __restrict__ csr_w, int E){
  int e = blockIdx.x*blockDim.x + threadIdx.x;
  if(e>=E) return;
  int s = src[e], d = dst[e];
  int pos = atomicAdd(&cursor[d], 1);
  csr_src[pos] = s;
  csr_w[pos]   = dinv[s];
}

// out[n][c] = sum_k in[n][k] * W[k][c]; one block = 256/COLS nodes,
// input rows staged in LDS (broadcast reads), W reads coalesced + L1-resident.
template<int K, int COLS>
__global__ __launch_bounds__(256) void k_gemm(const float* __restrict__ in,
                                              const float* __restrict__ W,
                                              float* __restrict__ out, int N){
  const int NODES = 256/COLS;
  __shared__ float srow[NODES*K];
  int n0 = blockIdx.x*NODES;
  for(int i=threadIdx.x; i<NODES*K; i+=256){
    int g = n0*K + i;
    srow[i] = (g < N*K) ? in[g] : 0.f;
  }
  __syncthreads();
  int c = threadIdx.x % COLS;
  int y = threadIdx.x / COLS;
  int n = n0+y;
  if(n>=N) return;
  float acc=0.f;
  #pragma unroll
  for(int k=0;k<K;k++) acc += srow[y*K+k]*W[k*COLS+c];
  out[n*COLS+c]=acc;
}

// AB[n][0..63] = h2[n] @ Wm1[0:64,:]; AB[n][64..127] = h2[n] @ Wm1[64:128,:]
__global__ __launch_bounds__(256) void k_gemm3(const float* __restrict__ h2,
                                               const float* __restrict__ Wm1,
                                               float* __restrict__ AB, int N){
  __shared__ float srow[2*HDIM];
  int n0 = blockIdx.x*2;
  for(int i=threadIdx.x; i<2*HDIM; i+=256){
    int g = n0*HDIM + i;
    srow[i] = (g < N*HDIM) ? h2[g] : 0.f;
  }
  __syncthreads();
  int c = threadIdx.x & 127;
  int y = threadIdx.x >> 7;
  int n = n0+y;
  if(n>=N) return;
  const float* Wcol = (c < HDIM) ? (Wm1 + c) : (Wm1 + HDIM*HDIM + (c-HDIM));
  float acc=0.f;
  #pragma unroll
  for(int k=0;k<HDIM;k++) acc += srow[y*HDIM+k]*Wcol[k*HDIM];
  AB[n*128+c]=acc;
}

// One wave per node v, lane = feature c. Gather-side aggregation over CSR row.
// 2-way unrolled so two neighbor gathers are in flight per iteration.
__global__ __launch_bounds__(256) void k_agg(const float* __restrict__ t,
                                             const int* __restrict__ csr_src,
                                             const float* __restrict__ csr_w,
                                             const int* __restrict__ row_start,
                                             const int* __restrict__ cnt,
                                             const float* __restrict__ dinv,
                                             const float* __restrict__ bias,
                                             float* __restrict__ out, int N){
  int c = threadIdx.x & 63;
  int v = blockIdx.x*4 + (threadIdx.x>>6);
  if(v>=N) return;
  float dv = dinv[v];
  float acc = t[(size_t)v*HDIM+c]*dv;   // self-loop term (x dv again at the end)
  int j0 = row_start[v];
  int j1 = j0 + cnt[v];
  int j = j0;
  for(; j+1<j1; j+=2){
    int   s0 = csr_src[j],   s1 = csr_src[j+1];
    float w0 = csr_w[j],     w1 = csr_w[j+1];
    float t0 = t[(size_t)s0*HDIM+c];
    float t1 = t[(size_t)s1*HDIM+c];
    acc += t0*w0;
    acc += t1*w1;
  }
  if(j<j1){
    int s = csr_src[j];
    acc += t[(size_t)s*HDIM+c]*csr_w[j];
  }
  float r = acc*dv + bias[c];
  out[(size_t)v*HDIM+c] = r>0.f ? r : 0.f;
}

// One thread per edge: acc[c] = bm2[c] + sum_k relu(A[s][k]+B[d][k]+bm1[k])*Wm2[k][c]
__global__ __launch_bounds__(256) void k_edge_mlp(const int* __restrict__ src,
                                                  const int* __restrict__ dst,
                                                  const float* __restrict__ AB,
                                                  const float* __restrict__ bm1,
                                                  const float* __restrict__ Wm2,
                                                  const float* __restrict__ bm2,
                                                  float* __restrict__ out, int E){
  int e = blockIdx.x*blockDim.x + threadIdx.x;
  if(e>=E) return;
  int s = src[e], d = dst[e];
  const float4* Af = (const float4*)(AB + (size_t)s*128);
  const float4* Bf = (const float4*)(AB + (size_t)d*128 + 64);
  const float4* bm1f = (const float4*)bm1;
  const float4* bm2f = (const float4*)bm2;
  float acc[CDIM];
  {
    float4 c0 = bm2f[0], c1 = bm2f[1], c2 = bm2f[2], c3 = bm2f[3];
    acc[0]=c0.x; acc[1]=c0.y; acc[2]=c0.z; acc[3]=c0.w;
    acc[4]=c1.x; acc[5]=c1.y; acc[6]=c1.z; acc[7]=c1.w;
    acc[8]=c2.x; acc[9]=c2.y; acc[10]=c2.z; acc[11]=c2.w;
    acc[12]=c3.x; acc[13]=c3.y; acc[14]=c3.z; acc[15]=c3.w;
  }
  #pragma unroll
  for(int k0=0;k0<16;k0++){
    float4 a = Af[k0];
    float4 b = Bf[k0];
    float4 bb = bm1f[k0];   // wave-uniform -> s_load
    float z0 = a.x+b.x+bb.x; z0 = z0>0.f? z0:0.f;
    float z1 = a.y+b.y+bb.y; z1 = z1>0.f? z1:0.f;
    float z2 = a.z+b.z+bb.z; z2 = z2>0.f? z2:0.f;
    float z3 = a.w+b.w+bb.w; z3 = z3>0.f? z3:0.f;
    #pragma unroll
    for(int c=0;c<CDIM;c++){
      acc[c] += z0 * Wm2[(k0*4+0)*CDIM + c];
      acc[c] += z1 * Wm2[(k0*4+1)*CDIM + c];
      acc[c] += z2 * Wm2[(k0*4+2)*CDIM + c];
      acc[c] += z3 * Wm2[(k0*4+3)*CDIM + c];
    }
  }
  float4* o = (float4*)(out + (size_t)e*CDIM);
  o[0] = make_float4(acc[0],acc[1],acc[2],acc[3]);
  o[1] = make_float4(acc[4],acc[5],acc[6],acc[7]);
  o[2] = make_float4(acc[8],acc[9],acc[10],acc[11]);
  o[3] = make_float4(acc[12],acc[13],acc[14],acc[15]);
}

extern "C" void kernel_launch(void* const* d_in, const int* in_sizes, int n_in,
                              void* d_out, int out_size, void* d_ws, size_t ws_size,
                              hipStream_t stream) {
  const float* x   = (const float*)d_in[0];
  const int*   ei  = (const int*)  d_in[1];
  const float* W1  = (const float*)d_in[2];
  const float* b1  = (const float*)d_in[3];
  const float* W2  = (const float*)d_in[4];
  const float* b2  = (const float*)d_in[5];
  const float* Wm1 = (const float*)d_in[6];
  const float* bm1 = (const float*)d_in[7];
  const float* Wm2 = (const float*)d_in[8];
  const float* bm2 = (const float*)d_in[9];
  float* out = (float*)d_out;

  const int N = in_sizes[0]/128;
  const int E = in_sizes[1]/2;
  const int* src = ei;
  const int* dst = ei + E;

  const int NB = ceil_div(N,256);   // blocks for node-wise scan kernels (196)

  // ws layout (256B-aligned). AB (25.6MB) aliases tbuf's region: tbuf is dead
  // by the time k_gemm3 writes AB, and hbuf (gemm3's input) sits after AB.
  char* ws = (char*)d_ws;
  size_t off = 0;
  auto alloc = [&](size_t bytes)->char*{
    char* p = ws + off; off += (bytes + 255) & ~(size_t)255; return p;
  };
  int*   cnt       = (int*)  alloc((size_t)N*4);
  int*   row_start = (int*)  alloc((size_t)N*4);
  int*   cursor    = (int*)  alloc((size_t)N*4);
  float* dinv      = (float*)alloc((size_t)N*4);
  int*   bsum      = (int*)  alloc((size_t)NB*4);
  int*   csr_src   = (int*)  alloc((size_t)E*4);
  float* csr_w     = (float*)alloc((size_t)E*4);
  float* AB        = (float*)alloc((size_t)N*128*4);  // also hosts tbuf in its low half
  float* tbuf      = AB;
  float* hbuf      = (float*)alloc((size_t)N*64*4);

  // --- CSR build ---
  k_zero_i32    <<<ceil_div(N,256),256,0,stream>>>(cnt, N);
  k_hist        <<<ceil_div(E,256),256,0,stream>>>(dst, cnt, E);
  k_blocksum    <<<NB,256,0,stream>>>(cnt, bsum, N);
  k_scan_bsums  <<<1,1024,0,stream>>>(bsum, NB);
  k_write_prefix<<<NB,256,0,stream>>>(cnt, bsum, row_start, cursor, dinv, N);
  k_fill        <<<ceil_div(E,256),256,0,stream>>>(src, dst, dinv, cursor, csr_src, csr_w, E);

  // --- layer 1 ---  (NODES per block = 256/COLS)
  k_gemm<128,64><<<ceil_div(N,256/64),256,0,stream>>>(x, W1, tbuf, N);
  k_agg        <<<ceil_div(N,4),256,0,stream>>>(tbuf, csr_src, csr_w, row_start, cnt,
                                                dinv, b1, hbuf, N);
  // --- layer 2 ---
  k_gemm<64,64><<<ceil_div(N,256/64),256,0,stream>>>(hbuf, W2, tbuf, N);
  k_agg        <<<ceil_div(N,4),256,0,stream>>>(tbuf, csr_src, csr_w, row_start, cnt,
                                                dinv, b2, hbuf, N);
  // --- edge MLP ---
  k_gemm3   <<<ceil_div(N,2),256,0,stream>>>(hbuf, Wm1, AB, N);
  k_edge_mlp<<<ceil_div(E,256),256,0,stream>>>(src, dst, AB, bm1, Wm2, bm2, out, E);
}

// Round 4
// 450.195 us; speedup vs baseline: 1.3643x; 1.1466x over previous
//
#include <hip/hip_runtime.h>
#include <hip/hip_bf16.h>

// GCN (2-layer, PyG-style symmetric norm + self loops) + edge MLP.
//  - CSR by dst (hist -> 3-level scan -> fill). No fp32 atomics.
//  - gcn_conv: t = h@W dense, then per-node gather-aggregate.
//  - Edge MLP: ef@Wm1 = A[src]+B[dst], A/B precomputed per node (k_gemm3).
//    Per edge: relu(A[s]+B[d]+bm1) @ Wm2 + bm2.
// R2: 3-level scan replaces single-block scan (was 111us @ 0.14% occ).
// R3: k_edge_mlp walks edges in CSR(dst) order -> B[d] row becomes wave-broadcast
//     (kills ~140MB of random B-gather misses); A row loads hoisted for MLP;
//     csr_w dropped (k_agg reads dinv[s], wave-uniform); k_agg 4-way unroll.

#define HDIM 64
#define CDIM 16

static inline int ceil_div(int a, int b){ return (a+b-1)/b; }

__global__ void k_zero_i32(int* p, int n){
  int i = blockIdx.x*blockDim.x + threadIdx.x;
  if(i<n) p[i]=0;
}

__global__ void k_hist(const int* __restrict__ dst, int* __restrict__ cnt, int E){
  int e = blockIdx.x*blockDim.x + threadIdx.x;
  if(e<E) atomicAdd(&cnt[dst[e]], 1);
}

// Level 1: per-block (256 nodes) sum of cnt -> bsum[block]
__global__ __launch_bounds__(256) void k_blocksum(const int* __restrict__ cnt,
                                                  int* __restrict__ bsum, int N){
  __shared__ int part[4];
  int i = blockIdx.x*256 + threadIdx.x;
  int v = (i<N) ? cnt[i] : 0;
  #pragma unroll
  for(int off=32; off>0; off>>=1) v += __shfl_down(v, off, 64);
  if((threadIdx.x & 63)==0) part[threadIdx.x>>6] = v;
  __syncthreads();
  if(threadIdx.x==0) bsum[blockIdx.x] = part[0]+part[1]+part[2]+part[3];
}

// Level 2: one block scans the per-block sums (nb <= 1024) -> exclusive prefix.
__global__ __launch_bounds__(1024) void k_scan_bsums(int* __restrict__ bsum, int nb){
  __shared__ int tmp[1024];
  int tid = threadIdx.x;
  int v = (tid<nb) ? bsum[tid] : 0;
  tmp[tid] = v; __syncthreads();
  for(int off=1; off<1024; off<<=1){
    int add = (tid>=off) ? tmp[tid-off] : 0;
    __syncthreads();
    tmp[tid] += add;
    __syncthreads();
  }
  if(tid<nb) bsum[tid] = tmp[tid] - v;   // exclusive
}

// Level 3: in-block exclusive scan of cnt + block offset -> row_start/cursor.
// Also computes dinv (needs only cnt).
__global__ __launch_bounds__(256) void k_write_prefix(const int* __restrict__ cnt,
                                                      const int* __restrict__ bsum,
                                                      int* __restrict__ row_start,
                                                      int* __restrict__ cursor,
                                                      float* __restrict__ dinv, int N){
  __shared__ int tmp[256];
  int tid = threadIdx.x;
  int i = blockIdx.x*256 + tid;
  int v = (i<N) ? cnt[i] : 0;
  tmp[tid] = v; __syncthreads();
  for(int off=1; off<256; off<<=1){
    int add = (tid>=off) ? tmp[tid-off] : 0;
    __syncthreads();
    tmp[tid] += add;
    __syncthreads();
  }
  if(i<N){
    int ex = bsum[blockIdx.x] + tmp[tid] - v;
    row_start[i] = ex;
    cursor[i]    = ex;
    dinv[i]      = 1.0f / sqrtf(1.0f + (float)v);  // deg >= 1 via self-loop
  }
}

__global__ void k_fill(const int* __restrict__ src, const int* __restrict__ dst,
                       int* __restrict__ cursor,
                       int* __restrict__ csr_src, int* __restrict__ csr_dst,
                       int* __restrict__ csr_eid, int E){
  int e = blockIdx.x*blockDim.x + threadIdx.x;
  if(e>=E) return;
  int s = src[e], d = dst[e];
  int pos = atomicAdd(&cursor[d], 1);
  csr_src[pos] = s;
  csr_dst[pos] = d;
  csr_eid[pos] = e;
}

// out[n][c] = sum_k in[n][k] * W[k][c]; one block = 256/COLS nodes,
// input rows staged in LDS (broadcast reads), W coalesced + cache-resident.
template<int K, int COLS>
__global__ __launch_bounds__(256) void k_gemm(const float* __restrict__ in,
                                              const float* __restrict__ W,
                                              float* __restrict__ out, int N){
  const int NODES = 256/COLS;
  __shared__ float srow[NODES*K];
  int n0 = blockIdx.x*NODES;
  for(int i=threadIdx.x; i<NODES*K; i+=256){
    int g = n0*K + i;
    srow[i] = (g < N*K) ? in[g] : 0.f;
  }
  __syncthreads();
  int c = threadIdx.x % COLS;
  int y = threadIdx.x / COLS;
  int n = n0+y;
  if(n>=N) return;
  float acc=0.f;
  #pragma unroll
  for(int k=0;k<K;k++) acc += srow[y*K+k]*W[k*COLS+c];
  out[n*COLS+c]=acc;
}

// AB[n][0..63] = h2[n] @ Wm1[0:64,:]; AB[n][64..127] = h2[n] @ Wm1[64:128,:]
__global__ __launch_bounds__(256) void k_gemm3(const float* __restrict__ h2,
                                               const float* __restrict__ Wm1,
                                               float* __restrict__ AB, int N){
  __shared__ float srow[2*HDIM];
  int n0 = blockIdx.x*2;
  for(int i=threadIdx.x; i<2*HDIM; i+=256){
    int g = n0*HDIM + i;
    srow[i] = (g < N*HDIM) ? h2[g] : 0.f;
  }
  __syncthreads();
  int c = threadIdx.x & 127;
  int y = threadIdx.x >> 7;
  int n = n0+y;
  if(n>=N) return;
  const float* Wcol = (c < HDIM) ? (Wm1 + c) : (Wm1 + HDIM*HDIM + (c-HDIM));
  float acc=0.f;
  #pragma unroll
  for(int k=0;k<HDIM;k++) acc += srow[y*HDIM+k]*Wcol[k*HDIM];
  AB[n*128+c]=acc;
}

// One wave per node v, lane = feature c. Gather-side aggregation over CSR row.
// 4-way unrolled so four neighbor gathers are in flight per iteration.
// Weight dinv[s] is a wave-uniform load (195KB table, L2-resident, broadcast).
__global__ __launch_bounds__(256) void k_agg(const float* __restrict__ t,
                                             const int* __restrict__ csr_src,
                                             const int* __restrict__ row_start,
                                             const int* __restrict__ cnt,
                                             const float* __restrict__ dinv,
                                             const float* __restrict__ bias,
                                             float* __restrict__ out, int N){
  int c = threadIdx.x & 63;
  int v = blockIdx.x*4 + (threadIdx.x>>6);
  if(v>=N) return;
  float dv = dinv[v];
  float acc = t[(size_t)v*HDIM+c]*dv;   // self-loop term (x dv again at the end)
  int j0 = row_start[v];
  int j1 = j0 + cnt[v];
  int j = j0;
  for(; j+3<j1; j+=4){
    int s0 = csr_src[j],   s1 = csr_src[j+1];
    int s2 = csr_src[j+2], s3 = csr_src[j+3];
    float w0 = dinv[s0], w1 = dinv[s1], w2 = dinv[s2], w3 = dinv[s3];
    float t0 = t[(size_t)s0*HDIM+c];
    float t1 = t[(size_t)s1*HDIM+c];
    float t2 = t[(size_t)s2*HDIM+c];
    float t3 = t[(size_t)s3*HDIM+c];
    acc += t0*w0; acc += t1*w1; acc += t2*w2; acc += t3*w3;
  }
  for(; j<j1; j++){
    int s = csr_src[j];
    acc += t[(size_t)s*HDIM+c]*dinv[s];
  }
  float r = acc*dv + bias[c];
  out[(size_t)v*HDIM+c] = r>0.f ? r : 0.f;
}

// Edge MLP in CSR(dst) order: thread j -> (s, d, eid). Consecutive threads share
// d (avg deg 16) -> B[d] reads broadcast/stream. A[s] stays random: all 16
// float4 loads issued up-front for memory-level parallelism.
__global__ __launch_bounds__(256) void k_edge_mlp(const int* __restrict__ csr_src,
                                                  const int* __restrict__ csr_dst,
                                                  const int* __restrict__ csr_eid,
                                                  const float* __restrict__ AB,
                                                  const float* __restrict__ bm1,
                                                  const float* __restrict__ Wm2,
                                                  const float* __restrict__ bm2,
                                                  float* __restrict__ out, int E){
  int j = blockIdx.x*blockDim.x + threadIdx.x;
  if(j>=E) return;
  int s = csr_src[j], d = csr_dst[j], eid = csr_eid[j];
  const float4* Af = (const float4*)(AB + (size_t)s*128);
  const float4* Bf = (const float4*)(AB + (size_t)d*128 + 64);
  const float4* bm1f = (const float4*)bm1;
  const float4* bm2f = (const float4*)bm2;

  float4 a[16];
  #pragma unroll
  for(int k0=0;k0<16;k0++) a[k0] = Af[k0];   // random-side gather, 16 in flight

  float acc[CDIM];
  {
    float4 c0 = bm2f[0], c1 = bm2f[1], c2 = bm2f[2], c3 = bm2f[3];
    acc[0]=c0.x; acc[1]=c0.y; acc[2]=c0.z; acc[3]=c0.w;
    acc[4]=c1.x; acc[5]=c1.y; acc[6]=c1.z; acc[7]=c1.w;
    acc[8]=c2.x; acc[9]=c2.y; acc[10]=c2.z; acc[11]=c2.w;
    acc[12]=c3.x; acc[13]=c3.y; acc[14]=c3.z; acc[15]=c3.w;
  }
  #pragma unroll
  for(int k0=0;k0<16;k0++){
    float4 b  = Bf[k0];     // same d across wave -> broadcast / L1-hit
    float4 bb = bm1f[k0];   // wave-uniform -> s_load
    float z0 = a[k0].x+b.x+bb.x; z0 = z0>0.f? z0:0.f;
    float z1 = a[k0].y+b.y+bb.y; z1 = z1>0.f? z1:0.f;
    float z2 = a[k0].z+b.z+bb.z; z2 = z2>0.f? z2:0.f;
    float z3 = a[k0].w+b.w+bb.w; z3 = z3>0.f? z3:0.f;
    #pragma unroll
    for(int c=0;c<CDIM;c++){
      acc[c] += z0 * Wm2[(k0*4+0)*CDIM + c];
      acc[c] += z1 * Wm2[(k0*4+1)*CDIM + c];
      acc[c] += z2 * Wm2[(k0*4+2)*CDIM + c];
      acc[c] += z3 * Wm2[(k0*4+3)*CDIM + c];
    }
  }
  float4* o = (float4*)(out + (size_t)eid*CDIM);
  o[0] = make_float4(acc[0],acc[1],acc[2],acc[3]);
  o[1] = make_float4(acc[4],acc[5],acc[6],acc[7]);
  o[2] = make_float4(acc[8],acc[9],acc[10],acc[11]);
  o[3] = make_float4(acc[12],acc[13],acc[14],acc[15]);
}

extern "C" void kernel_launch(void* const* d_in, const int* in_sizes, int n_in,
                              void* d_out, int out_size, void* d_ws, size_t ws_size,
                              hipStream_t stream) {
  const float* x   = (const float*)d_in[0];
  const int*   ei  = (const int*)  d_in[1];
  const float* W1  = (const float*)d_in[2];
  const float* b1  = (const float*)d_in[3];
  const float* W2  = (const float*)d_in[4];
  const float* b2  = (const float*)d_in[5];
  const float* Wm1 = (const float*)d_in[6];
  const float* bm1 = (const float*)d_in[7];
  const float* Wm2 = (const float*)d_in[8];
  const float* bm2 = (const float*)d_in[9];
  float* out = (float*)d_out;

  const int N = in_sizes[0]/128;
  const int E = in_sizes[1]/2;
  const int* src = ei;
  const int* dst = ei + E;

  const int NB = ceil_div(N,256);

  // ws layout (256B-aligned). AB (25.6MB) aliases tbuf's region: tbuf is dead
  // by the time k_gemm3 writes AB, and hbuf (gemm3's input) sits after AB.
  char* ws = (char*)d_ws;
  size_t off = 0;
  auto alloc = [&](size_t bytes)->char*{
    char* p = ws + off; off += (bytes + 255) & ~(size_t)255; return p;
  };
  int*   cnt       = (int*)  alloc((size_t)N*4);
  int*   row_start = (int*)  alloc((size_t)N*4);
  int*   cursor    = (int*)  alloc((size_t)N*4);
  float* dinv      = (float*)alloc((size_t)N*4);
  int*   bsum      = (int*)  alloc((size_t)NB*4);
  int*   csr_src   = (int*)  alloc((size_t)E*4);
  int*   csr_dst   = (int*)  alloc((size_t)E*4);
  int*   csr_eid   = (int*)  alloc((size_t)E*4);
  float* AB        = (float*)alloc((size_t)N*128*4);  // also hosts tbuf in its low half
  float* tbuf      = AB;
  float* hbuf      = (float*)alloc((size_t)N*64*4);

  // --- CSR build ---
  k_zero_i32    <<<ceil_div(N,256),256,0,stream>>>(cnt, N);
  k_hist        <<<ceil_div(E,256),256,0,stream>>>(dst, cnt, E);
  k_blocksum    <<<NB,256,0,stream>>>(cnt, bsum, N);
  k_scan_bsums  <<<1,1024,0,stream>>>(bsum, NB);
  k_write_prefix<<<NB,256,0,stream>>>(cnt, bsum, row_start, cursor, dinv, N);
  k_fill        <<<ceil_div(E,256),256,0,stream>>>(src, dst, cursor,
                                                   csr_src, csr_dst, csr_eid, E);

  // --- layer 1 ---
  k_gemm<128,64><<<ceil_div(N,256/64),256,0,stream>>>(x, W1, tbuf, N);
  k_agg        <<<ceil_div(N,4),256,0,stream>>>(tbuf, csr_src, row_start, cnt,
                                                dinv, b1, hbuf, N);
  // --- layer 2 ---
  k_gemm<64,64><<<ceil_div(N,256/64),256,0,stream>>>(hbuf, W2, tbuf, N);
  k_agg        <<<ceil_div(N,4),256,0,stream>>>(tbuf, csr_src, row_start, cnt,
                                                dinv, b2, hbuf, N);
  // --- edge MLP ---
  k_gemm3   <<<ceil_div(N,2),256,0,stream>>>(hbuf, Wm1, AB, N);
  k_edge_mlp<<<ceil_div(E,256),256,0,stream>>>(csr_src, csr_dst, csr_eid, AB,
                                               bm1, Wm2, bm2, out, E);
}

// Round 5
// 433.271 us; speedup vs baseline: 1.4176x; 1.0391x over previous
//
#include <hip/hip_runtime.h>
#include <hip/hip_bf16.h>

// GCN (2-layer, PyG-style symmetric norm + self loops) + edge MLP.
//  - CSR by dst (hist -> 3-level scan -> fill). No fp32 atomics.
//  - gcn_conv: t = h@W dense, then per-node gather-aggregate.
//  - Edge MLP: ef@Wm1 = A[src]+B[dst], A/B precomputed per node.
//    Per edge: relu(A[s]+B[d]+bm1) @ Wm2 + bm2.
// R2: 3-level scan replaces single-block scan (was 111us @ 0.14% occ).
// R3: k_edge_mlp in CSR(dst) order -> B[d] wave-broadcast; FETCH 295->121MB,
//     107->63.6us.
// R4: fuse the per-node GEMMs (h@W2, h2@Wm1) into k_agg's epilogue via LDS
//     row-broadcast: deletes k_gemm<64,64> + k_gemm3 and 51.2MB of hbuf
//     round-trip traffic. Pipeline: gemm1 -> aggF(W2) -> aggF(Wm1) -> edge_mlp.

#define HDIM 64
#define CDIM 16

static inline int ceil_div(int a, int b){ return (a+b-1)/b; }

__global__ void k_zero_i32(int* p, int n){
  int i = blockIdx.x*blockDim.x + threadIdx.x;
  if(i<n) p[i]=0;
}

__global__ void k_hist(const int* __restrict__ dst, int* __restrict__ cnt, int E){
  int e = blockIdx.x*blockDim.x + threadIdx.x;
  if(e<E) atomicAdd(&cnt[dst[e]], 1);
}

// Level 1: per-block (256 nodes) sum of cnt -> bsum[block]
__global__ __launch_bounds__(256) void k_blocksum(const int* __restrict__ cnt,
                                                  int* __restrict__ bsum, int N){
  __shared__ int part[4];
  int i = blockIdx.x*256 + threadIdx.x;
  int v = (i<N) ? cnt[i] : 0;
  #pragma unroll
  for(int off=32; off>0; off>>=1) v += __shfl_down(v, off, 64);
  if((threadIdx.x & 63)==0) part[threadIdx.x>>6] = v;
  __syncthreads();
  if(threadIdx.x==0) bsum[blockIdx.x] = part[0]+part[1]+part[2]+part[3];
}

// Level 2: one block scans the per-block sums (nb <= 1024) -> exclusive prefix.
__global__ __launch_bounds__(1024) void k_scan_bsums(int* __restrict__ bsum, int nb){
  __shared__ int tmp[1024];
  int tid = threadIdx.x;
  int v = (tid<nb) ? bsum[tid] : 0;
  tmp[tid] = v; __syncthreads();
  for(int off=1; off<1024; off<<=1){
    int add = (tid>=off) ? tmp[tid-off] : 0;
    __syncthreads();
    tmp[tid] += add;
    __syncthreads();
  }
  if(tid<nb) bsum[tid] = tmp[tid] - v;   // exclusive
}

// Level 3: in-block exclusive scan of cnt + block offset -> row_start/cursor.
// Also computes dinv (needs only cnt).
__global__ __launch_bounds__(256) void k_write_prefix(const int* __restrict__ cnt,
                                                      const int* __restrict__ bsum,
                                                      int* __restrict__ row_start,
                                                      int* __restrict__ cursor,
                                                      float* __restrict__ dinv, int N){
  __shared__ int tmp[256];
  int tid = threadIdx.x;
  int i = blockIdx.x*256 + tid;
  int v = (i<N) ? cnt[i] : 0;
  tmp[tid] = v; __syncthreads();
  for(int off=1; off<256; off<<=1){
    int add = (tid>=off) ? tmp[tid-off] : 0;
    __syncthreads();
    tmp[tid] += add;
    __syncthreads();
  }
  if(i<N){
    int ex = bsum[blockIdx.x] + tmp[tid] - v;
    row_start[i] = ex;
    cursor[i]    = ex;
    dinv[i]      = 1.0f / sqrtf(1.0f + (float)v);  // deg >= 1 via self-loop
  }
}

__global__ void k_fill(const int* __restrict__ src, const int* __restrict__ dst,
                       int* __restrict__ cursor,
                       int* __restrict__ csr_src, int* __restrict__ csr_dst,
                       int* __restrict__ csr_eid, int E){
  int e = blockIdx.x*blockDim.x + threadIdx.x;
  if(e>=E) return;
  int s = src[e], d = dst[e];
  int pos = atomicAdd(&cursor[d], 1);
  csr_src[pos] = s;
  csr_dst[pos] = d;
  csr_eid[pos] = e;
}

// out[n][c] = sum_k in[n][k] * W[k][c]; one block = 4 nodes (COLS=64),
// input rows staged in LDS, W coalesced + L1-resident.
template<int K, int COLS>
__global__ __launch_bounds__(256) void k_gemm(const float* __restrict__ in,
                                              const float* __restrict__ W,
                                              float* __restrict__ out, int N){
  const int NODES = 256/COLS;
  __shared__ float srow[NODES*K];
  int n0 = blockIdx.x*NODES;
  for(int i=threadIdx.x; i<NODES*K; i+=256){
    int g = n0*K + i;
    srow[i] = (g < N*K) ? in[g] : 0.f;
  }
  __syncthreads();
  int c = threadIdx.x % COLS;
  int y = threadIdx.x / COLS;
  int n = n0+y;
  if(n>=N) return;
  float acc=0.f;
  #pragma unroll
  for(int k=0;k<K;k++) acc += srow[y*K+k]*W[k*COLS+c];
  out[n*COLS+c]=acc;
}

// Fused: gather-aggregate (CSR row, 4 gathers in flight) -> relu(acc*dv + b)
// -> per-node GEMM epilogue against Wepi (GROUPS*64 x 64, row-major) via LDS
// row broadcast. GROUPS=1: t2 = h1@W2. GROUPS=2: AB = h2@Wm1 (A then B half).
// No early returns: __syncthreads() is executed by all threads.
template<int GROUPS>
__global__ __launch_bounds__(256) void k_agg_fused(const float* __restrict__ t,
                                                   const int* __restrict__ csr_src,
                                                   const int* __restrict__ row_start,
                                                   const int* __restrict__ cnt,
                                                   const float* __restrict__ dinv,
                                                   const float* __restrict__ bias,
                                                   const float* __restrict__ Wepi,
                                                   float* __restrict__ outbuf, int N){
  __shared__ float srow[4][HDIM];
  int lane = threadIdx.x & 63;
  int w    = threadIdx.x >> 6;
  int v    = blockIdx.x*4 + w;
  bool act = (v < N);
  int vv   = act ? v : 0;

  float dv  = dinv[vv];
  float acc = t[(size_t)vv*HDIM + lane] * dv;   // self-loop term
  int j0 = act ? row_start[vv] : 0;
  int j1 = act ? (j0 + cnt[vv]) : 0;
  int j = j0;
  for(; j+3<j1; j+=4){
    int s0 = csr_src[j],   s1 = csr_src[j+1];
    int s2 = csr_src[j+2], s3 = csr_src[j+3];
    float w0 = dinv[s0], w1 = dinv[s1], w2 = dinv[s2], w3 = dinv[s3];
    float t0 = t[(size_t)s0*HDIM+lane];
    float t1 = t[(size_t)s1*HDIM+lane];
    float t2 = t[(size_t)s2*HDIM+lane];
    float t3 = t[(size_t)s3*HDIM+lane];
    acc += t0*w0; acc += t1*w1; acc += t2*w2; acc += t3*w3;
  }
  for(; j<j1; j++){
    int s = csr_src[j];
    acc += t[(size_t)s*HDIM+lane]*dinv[s];
  }
  float r = acc*dv + bias[lane];
  r = r>0.f ? r : 0.f;                 // h row for this node, one value per lane
  srow[w][lane] = r;
  __syncthreads();

  float s_out[GROUPS];
  #pragma unroll
  for(int g=0; g<GROUPS; g++) s_out[g] = 0.f;
  #pragma unroll
  for(int k=0; k<HDIM; k++){
    float hv = srow[w][k];             // broadcast LDS read
    #pragma unroll
    for(int g=0; g<GROUPS; g++)
      s_out[g] += hv * Wepi[(size_t)(g*HDIM + k)*HDIM + lane];  // coalesced, L1-hit
  }
  if(act){
    #pragma unroll
    for(int g=0; g<GROUPS; g++)
      outbuf[(size_t)v*(GROUPS*HDIM) + g*HDIM + lane] = s_out[g];
  }
}

// Edge MLP in CSR(dst) order: thread j -> (s, d, eid). Consecutive threads share
// d -> B[d] reads broadcast/stream. A[s] random: 16 float4 loads in flight.
__global__ __launch_bounds__(256) void k_edge_mlp(const int* __restrict__ csr_src,
                                                  const int* __restrict__ csr_dst,
                                                  const int* __restrict__ csr_eid,
                                                  const float* __restrict__ AB,
                                                  const float* __restrict__ bm1,
                                                  const float* __restrict__ Wm2,
                                                  const float* __restrict__ bm2,
                                                  float* __restrict__ out, int E){
  int j = blockIdx.x*blockDim.x + threadIdx.x;
  if(j>=E) return;
  int s = csr_src[j], d = csr_dst[j], eid = csr_eid[j];
  const float4* Af = (const float4*)(AB + (size_t)s*128);
  const float4* Bf = (const float4*)(AB + (size_t)d*128 + 64);
  const float4* bm1f = (const float4*)bm1;
  const float4* bm2f = (const float4*)bm2;

  float4 a[16];
  #pragma unroll
  for(int k0=0;k0<16;k0++) a[k0] = Af[k0];   // random-side gather, 16 in flight

  float acc[CDIM];
  {
    float4 c0 = bm2f[0], c1 = bm2f[1], c2 = bm2f[2], c3 = bm2f[3];
    acc[0]=c0.x; acc[1]=c0.y; acc[2]=c0.z; acc[3]=c0.w;
    acc[4]=c1.x; acc[5]=c1.y; acc[6]=c1.z; acc[7]=c1.w;
    acc[8]=c2.x; acc[9]=c2.y; acc[10]=c2.z; acc[11]=c2.w;
    acc[12]=c3.x; acc[13]=c3.y; acc[14]=c3.z; acc[15]=c3.w;
  }
  #pragma unroll
  for(int k0=0;k0<16;k0++){
    float4 b  = Bf[k0];     // same d across wave -> broadcast / L1-hit
    float4 bb = bm1f[k0];   // wave-uniform -> s_load
    float z0 = a[k0].x+b.x+bb.x; z0 = z0>0.f? z0:0.f;
    float z1 = a[k0].y+b.y+bb.y; z1 = z1>0.f? z1:0.f;
    float z2 = a[k0].z+b.z+bb.z; z2 = z2>0.f? z2:0.f;
    float z3 = a[k0].w+b.w+bb.w; z3 = z3>0.f? z3:0.f;
    #pragma unroll
    for(int c=0;c<CDIM;c++){
      acc[c] += z0 * Wm2[(k0*4+0)*CDIM + c];
      acc[c] += z1 * Wm2[(k0*4+1)*CDIM + c];
      acc[c] += z2 * Wm2[(k0*4+2)*CDIM + c];
      acc[c] += z3 * Wm2[(k0*4+3)*CDIM + c];
    }
  }
  float4* o = (float4*)(out + (size_t)eid*CDIM);
  o[0] = make_float4(acc[0],acc[1],acc[2],acc[3]);
  o[1] = make_float4(acc[4],acc[5],acc[6],acc[7]);
  o[2] = make_float4(acc[8],acc[9],acc[10],acc[11]);
  o[3] = make_float4(acc[12],acc[13],acc[14],acc[15]);
}

extern "C" void kernel_launch(void* const* d_in, const int* in_sizes, int n_in,
                              void* d_out, int out_size, void* d_ws, size_t ws_size,
                              hipStream_t stream) {
  const float* x   = (const float*)d_in[0];
  const int*   ei  = (const int*)  d_in[1];
  const float* W1  = (const float*)d_in[2];
  const float* b1  = (const float*)d_in[3];
  const float* W2  = (const float*)d_in[4];
  const float* b2  = (const float*)d_in[5];
  const float* Wm1 = (const float*)d_in[6];
  const float* bm1 = (const float*)d_in[7];
  const float* Wm2 = (const float*)d_in[8];
  const float* bm2 = (const float*)d_in[9];
  float* out = (float*)d_out;

  const int N = in_sizes[0]/128;
  const int E = in_sizes[1]/2;
  const int* src = ei;
  const int* dst = ei + E;

  const int NB = ceil_div(N,256);

  // ws layout (256B-aligned). t1 (N*64) aliases AB's low half: t1 is dead
  // (last read by aggF<1>) before aggF<2> writes AB.
  char* ws = (char*)d_ws;
  size_t off = 0;
  auto alloc = [&](size_t bytes)->char*{
    char* p = ws + off; off += (bytes + 255) & ~(size_t)255; return p;
  };
  int*   cnt       = (int*)  alloc((size_t)N*4);
  int*   row_start = (int*)  alloc((size_t)N*4);
  int*   cursor    = (int*)  alloc((size_t)N*4);
  float* dinv      = (float*)alloc((size_t)N*4);
  int*   bsum      = (int*)  alloc((size_t)NB*4);
  int*   csr_src   = (int*)  alloc((size_t)E*4);
  int*   csr_dst   = (int*)  alloc((size_t)E*4);
  int*   csr_eid   = (int*)  alloc((size_t)E*4);
  float* AB        = (float*)alloc((size_t)N*128*4);
  float* t1        = AB;                               // alias: low 12.8MB of AB
  float* t2        = (float*)alloc((size_t)N*64*4);

  // --- CSR build ---
  k_zero_i32    <<<ceil_div(N,256),256,0,stream>>>(cnt, N);
  k_hist        <<<ceil_div(E,256),256,0,stream>>>(dst, cnt, E);
  k_blocksum    <<<NB,256,0,stream>>>(cnt, bsum, N);
  k_scan_bsums  <<<1,1024,0,stream>>>(bsum, NB);
  k_write_prefix<<<NB,256,0,stream>>>(cnt, bsum, row_start, cursor, dinv, N);
  k_fill        <<<ceil_div(E,256),256,0,stream>>>(src, dst, cursor,
                                                   csr_src, csr_dst, csr_eid, E);

  // --- layer 1: t1 = x@W1 ---
  k_gemm<128,64><<<ceil_div(N,4),256,0,stream>>>(x, W1, t1, N);
  // --- agg1 + fused (h1@W2): t2 ---
  k_agg_fused<1><<<ceil_div(N,4),256,0,stream>>>(t1, csr_src, row_start, cnt,
                                                 dinv, b1, W2, t2, N);
  // --- agg2 + fused (h2@Wm1): AB ---
  k_agg_fused<2><<<ceil_div(N,4),256,0,stream>>>(t2, csr_src, row_start, cnt,
                                                 dinv, b2, Wm1, AB, N);
  // --- edge MLP ---
  k_edge_mlp<<<ceil_div(E,256),256,0,stream>>>(csr_src, csr_dst, csr_eid, AB,
                                               bm1, Wm2, bm2, out, E);
}

// Round 6
// 408.446 us; speedup vs baseline: 1.5038x; 1.0608x over previous
//
#include <hip/hip_runtime.h>
#include <hip/hip_bf16.h>

// GCN (2-layer, PyG-style symmetric norm + self loops) + edge MLP.
//  - CSR by dst (hist -> 3-level scan -> fill). No fp32 atomics.
//  - gcn_conv: t = h@W dense, then per-node gather-aggregate.
//  - Edge MLP: ef@Wm1 = A[src]+B[dst], A/B precomputed per node.
//    Per edge: relu(A[s]+B[d]+bm1) @ Wm2 + bm2.
// R2: 3-level scan replaces single-block scan (was 111us @ 0.14% occ).
// R3: k_edge_mlp in CSR(dst) order -> B[d] wave-broadcast; 107->63.6us.
// R4: per-node GEMMs fused into k_agg epilogue (LDS row-broadcast).
// R5: k_agg gather loop de-serialized: cooperative batch index/weight load
//     (1 coalesced load + 1 gather per 64 edges) + readlane broadcast, 4
//     accumulators -> removes the s_load(csr)->s_load(dinv)->v_load chain
//     that left only 4 serialized loads in flight per wave (VALUBusy 31%,
//     BW 17% => issue-latency-bound).

#define HDIM 64
#define CDIM 16

static inline int ceil_div(int a, int b){ return (a+b-1)/b; }

__global__ void k_zero_i32(int* p, int n){
  int i = blockIdx.x*blockDim.x + threadIdx.x;
  if(i<n) p[i]=0;
}

__global__ void k_hist(const int* __restrict__ dst, int* __restrict__ cnt, int E){
  int e = blockIdx.x*blockDim.x + threadIdx.x;
  if(e<E) atomicAdd(&cnt[dst[e]], 1);
}

// Level 1: per-block (256 nodes) sum of cnt -> bsum[block]
__global__ __launch_bounds__(256) void k_blocksum(const int* __restrict__ cnt,
                                                  int* __restrict__ bsum, int N){
  __shared__ int part[4];
  int i = blockIdx.x*256 + threadIdx.x;
  int v = (i<N) ? cnt[i] : 0;
  #pragma unroll
  for(int off=32; off>0; off>>=1) v += __shfl_down(v, off, 64);
  if((threadIdx.x & 63)==0) part[threadIdx.x>>6] = v;
  __syncthreads();
  if(threadIdx.x==0) bsum[blockIdx.x] = part[0]+part[1]+part[2]+part[3];
}

// Level 2: one block scans the per-block sums (nb <= 1024) -> exclusive prefix.
__global__ __launch_bounds__(1024) void k_scan_bsums(int* __restrict__ bsum, int nb){
  __shared__ int tmp[1024];
  int tid = threadIdx.x;
  int v = (tid<nb) ? bsum[tid] : 0;
  tmp[tid] = v; __syncthreads();
  for(int off=1; off<1024; off<<=1){
    int add = (tid>=off) ? tmp[tid-off] : 0;
    __syncthreads();
    tmp[tid] += add;
    __syncthreads();
  }
  if(tid<nb) bsum[tid] = tmp[tid] - v;   // exclusive
}

// Level 3: in-block exclusive scan of cnt + block offset -> row_start/cursor.
// Also computes dinv (needs only cnt).
__global__ __launch_bounds__(256) void k_write_prefix(const int* __restrict__ cnt,
                                                      const int* __restrict__ bsum,
                                                      int* __restrict__ row_start,
                                                      int* __restrict__ cursor,
                                                      float* __restrict__ dinv, int N){
  __shared__ int tmp[256];
  int tid = threadIdx.x;
  int i = blockIdx.x*256 + tid;
  int v = (i<N) ? cnt[i] : 0;
  tmp[tid] = v; __syncthreads();
  for(int off=1; off<256; off<<=1){
    int add = (tid>=off) ? tmp[tid-off] : 0;
    __syncthreads();
    tmp[tid] += add;
    __syncthreads();
  }
  if(i<N){
    int ex = bsum[blockIdx.x] + tmp[tid] - v;
    row_start[i] = ex;
    cursor[i]    = ex;
    dinv[i]      = 1.0f / sqrtf(1.0f + (float)v);  // deg >= 1 via self-loop
  }
}

__global__ void k_fill(const int* __restrict__ src, const int* __restrict__ dst,
                       int* __restrict__ cursor,
                       int* __restrict__ csr_src, int* __restrict__ csr_dst,
                       int* __restrict__ csr_eid, int E){
  int e = blockIdx.x*blockDim.x + threadIdx.x;
  if(e>=E) return;
  int s = src[e], d = dst[e];
  int pos = atomicAdd(&cursor[d], 1);
  csr_src[pos] = s;
  csr_dst[pos] = d;
  csr_eid[pos] = e;
}

// out[n][c] = sum_k in[n][k] * W[k][c]; one block = 4 nodes (COLS=64),
// input rows staged in LDS, W coalesced + L1-resident.
template<int K, int COLS>
__global__ __launch_bounds__(256) void k_gemm(const float* __restrict__ in,
                                              const float* __restrict__ W,
                                              float* __restrict__ out, int N){
  const int NODES = 256/COLS;
  __shared__ float srow[NODES*K];
  int n0 = blockIdx.x*NODES;
  for(int i=threadIdx.x; i<NODES*K; i+=256){
    int g = n0*K + i;
    srow[i] = (g < N*K) ? in[g] : 0.f;
  }
  __syncthreads();
  int c = threadIdx.x % COLS;
  int y = threadIdx.x / COLS;
  int n = n0+y;
  if(n>=N) return;
  float acc=0.f;
  #pragma unroll
  for(int k=0;k<K;k++) acc += srow[y*K+k]*W[k*COLS+c];
  out[n*COLS+c]=acc;
}

// Fused: gather-aggregate -> relu(acc*dv + b) -> per-node GEMM epilogue against
// Wepi (GROUPS*64 x 64 row-major) via LDS row broadcast.
// Gather loop: batch of <=64 edges; lane l cooperatively loads edge (b+l)'s
// src index (coalesced) and dinv[src] (4B gather); per-edge broadcast via
// readlane (index -> SGPR base for scalar-addressed gather, weight -> SGPR
// FMA operand). 4 accumulators keep 4 independent 256B gathers in flight.
template<int GROUPS>
__global__ __launch_bounds__(256) void k_agg_fused(const float* __restrict__ t,
                                                   const int* __restrict__ csr_src,
                                                   const int* __restrict__ row_start,
                                                   const int* __restrict__ cnt,
                                                   const float* __restrict__ dinv,
                                                   const float* __restrict__ bias,
                                                   const float* __restrict__ Wepi,
                                                   float* __restrict__ outbuf, int N){
  __shared__ float srow[4][HDIM];
  int lane = threadIdx.x & 63;
  int w    = threadIdx.x >> 6;
  int v    = blockIdx.x*4 + w;
  bool act = (v < N);
  int vv   = act ? v : 0;

  float dv   = dinv[vv];
  float acc0 = t[(size_t)vv*HDIM + lane] * dv;   // self-loop term
  float acc1 = 0.f, acc2 = 0.f, acc3 = 0.f;
  int j0  = act ? row_start[vv] : 0;
  int deg = act ? cnt[vv] : 0;

  for(int b=0; b<deg; b+=64){
    int m = deg - b; if(m>64) m=64;
    int   idxv = 0;
    float wv   = 0.f;
    if(lane < m){
      idxv = csr_src[j0 + b + lane];   // one coalesced load covers the batch
      wv   = dinv[idxv];               // 4B gather, per-lane
    }
    int k=0;
    for(; k+3<m; k+=4){
      int s0 = __builtin_amdgcn_readlane(idxv, k);
      int s1 = __builtin_amdgcn_readlane(idxv, k+1);
      int s2 = __builtin_amdgcn_readlane(idxv, k+2);
      int s3 = __builtin_amdgcn_readlane(idxv, k+3);
      float w0 = __uint_as_float(__builtin_amdgcn_readlane(__float_as_uint(wv), k));
      float w1 = __uint_as_float(__builtin_amdgcn_readlane(__float_as_uint(wv), k+1));
      float w2 = __uint_as_float(__builtin_amdgcn_readlane(__float_as_uint(wv), k+2));
      float w3 = __uint_as_float(__builtin_amdgcn_readlane(__float_as_uint(wv), k+3));
      float t0 = t[(size_t)s0*HDIM+lane];
      float t1 = t[(size_t)s1*HDIM+lane];
      float t2 = t[(size_t)s2*HDIM+lane];
      float t3 = t[(size_t)s3*HDIM+lane];
      acc0 += t0*w0; acc1 += t1*w1; acc2 += t2*w2; acc3 += t3*w3;
    }
    for(; k<m; k++){
      int   s = __builtin_amdgcn_readlane(idxv, k);
      float wk = __uint_as_float(__builtin_amdgcn_readlane(__float_as_uint(wv), k));
      acc0 += t[(size_t)s*HDIM+lane]*wk;
    }
  }
  float acc = (acc0+acc1)+(acc2+acc3);
  float r = acc*dv + bias[lane];
  r = r>0.f ? r : 0.f;                 // h row for this node, one value per lane
  srow[w][lane] = r;
  __syncthreads();

  float s_out[GROUPS];
  #pragma unroll
  for(int g=0; g<GROUPS; g++) s_out[g] = 0.f;
  #pragma unroll
  for(int k=0; k<HDIM; k++){
    float hv = srow[w][k];             // broadcast LDS read
    #pragma unroll
    for(int g=0; g<GROUPS; g++)
      s_out[g] += hv * Wepi[(size_t)(g*HDIM + k)*HDIM + lane];  // coalesced, L1-hit
  }
  if(act){
    #pragma unroll
    for(int g=0; g<GROUPS; g++)
      outbuf[(size_t)v*(GROUPS*HDIM) + g*HDIM + lane] = s_out[g];
  }
}

// Edge MLP in CSR(dst) order: thread j -> (s, d, eid). Consecutive threads share
// d -> B[d] reads broadcast/stream. A[s] random: 16 float4 loads in flight.
__global__ __launch_bounds__(256) void k_edge_mlp(const int* __restrict__ csr_src,
                                                  const int* __restrict__ csr_dst,
                                                  const int* __restrict__ csr_eid,
                                                  const float* __restrict__ AB,
                                                  const float* __restrict__ bm1,
                                                  const float* __restrict__ Wm2,
                                                  const float* __restrict__ bm2,
                                                  float* __restrict__ out, int E){
  int j = blockIdx.x*blockDim.x + threadIdx.x;
  if(j>=E) return;
  int s = csr_src[j], d = csr_dst[j], eid = csr_eid[j];
  const float4* Af = (const float4*)(AB + (size_t)s*128);
  const float4* Bf = (const float4*)(AB + (size_t)d*128 + 64);
  const float4* bm1f = (const float4*)bm1;
  const float4* bm2f = (const float4*)bm2;

  float4 a[16];
  #pragma unroll
  for(int k0=0;k0<16;k0++) a[k0] = Af[k0];   // random-side gather, 16 in flight

  float acc[CDIM];
  {
    float4 c0 = bm2f[0], c1 = bm2f[1], c2 = bm2f[2], c3 = bm2f[3];
    acc[0]=c0.x; acc[1]=c0.y; acc[2]=c0.z; acc[3]=c0.w;
    acc[4]=c1.x; acc[5]=c1.y; acc[6]=c1.z; acc[7]=c1.w;
    acc[8]=c2.x; acc[9]=c2.y; acc[10]=c2.z; acc[11]=c2.w;
    acc[12]=c3.x; acc[13]=c3.y; acc[14]=c3.z; acc[15]=c3.w;
  }
  #pragma unroll
  for(int k0=0;k0<16;k0++){
    float4 b  = Bf[k0];     // same d across wave -> broadcast / L1-hit
    float4 bb = bm1f[k0];   // wave-uniform -> s_load
    float z0 = a[k0].x+b.x+bb.x; z0 = z0>0.f? z0:0.f;
    float z1 = a[k0].y+b.y+bb.y; z1 = z1>0.f? z1:0.f;
    float z2 = a[k0].z+b.z+bb.z; z2 = z2>0.f? z2:0.f;
    float z3 = a[k0].w+b.w+bb.w; z3 = z3>0.f? z3:0.f;
    #pragma unroll
    for(int c=0;c<CDIM;c++){
      acc[c] += z0 * Wm2[(k0*4+0)*CDIM + c];
      acc[c] += z1 * Wm2[(k0*4+1)*CDIM + c];
      acc[c] += z2 * Wm2[(k0*4+2)*CDIM + c];
      acc[c] += z3 * Wm2[(k0*4+3)*CDIM + c];
    }
  }
  float4* o = (float4*)(out + (size_t)eid*CDIM);
  o[0] = make_float4(acc[0],acc[1],acc[2],acc[3]);
  o[1] = make_float4(acc[4],acc[5],acc[6],acc[7]);
  o[2] = make_float4(acc[8],acc[9],acc[10],acc[11]);
  o[3] = make_float4(acc[12],acc[13],acc[14],acc[15]);
}

extern "C" void kernel_launch(void* const* d_in, const int* in_sizes, int n_in,
                              void* d_out, int out_size, void* d_ws, size_t ws_size,
                              hipStream_t stream) {
  const float* x   = (const float*)d_in[0];
  const int*   ei  = (const int*)  d_in[1];
  const float* W1  = (const float*)d_in[2];
  const float* b1  = (const float*)d_in[3];
  const float* W2  = (const float*)d_in[4];
  const float* b2  = (const float*)d_in[5];
  const float* Wm1 = (const float*)d_in[6];
  const float* bm1 = (const float*)d_in[7];
  const float* Wm2 = (const float*)d_in[8];
  const float* bm2 = (const float*)d_in[9];
  float* out = (float*)d_out;

  const int N = in_sizes[0]/128;
  const int E = in_sizes[1]/2;
  const int* src = ei;
  const int* dst = ei + E;

  const int NB = ceil_div(N,256);

  // ws layout (256B-aligned). t1 (N*64) aliases AB's low half: t1 is dead
  // (last read by aggF<1>) before aggF<2> writes AB.
  char* ws = (char*)d_ws;
  size_t off = 0;
  auto alloc = [&](size_t bytes)->char*{
    char* p = ws + off; off += (bytes + 255) & ~(size_t)255; return p;
  };
  int*   cnt       = (int*)  alloc((size_t)N*4);
  int*   row_start = (int*)  alloc((size_t)N*4);
  int*   cursor    = (int*)  alloc((size_t)N*4);
  float* dinv      = (float*)alloc((size_t)N*4);
  int*   bsum      = (int*)  alloc((size_t)NB*4);
  int*   csr_src   = (int*)  alloc((size_t)E*4);
  int*   csr_dst   = (int*)  alloc((size_t)E*4);
  int*   csr_eid   = (int*)  alloc((size_t)E*4);
  float* AB        = (float*)alloc((size_t)N*128*4);
  float* t1        = AB;                               // alias: low 12.8MB of AB
  float* t2        = (float*)alloc((size_t)N*64*4);

  // --- CSR build ---
  k_zero_i32    <<<ceil_div(N,256),256,0,stream>>>(cnt, N);
  k_hist        <<<ceil_div(E,256),256,0,stream>>>(dst, cnt, E);
  k_blocksum    <<<NB,256,0,stream>>>(cnt, bsum, N);
  k_scan_bsums  <<<1,1024,0,stream>>>(bsum, NB);
  k_write_prefix<<<NB,256,0,stream>>>(cnt, bsum, row_start, cursor, dinv, N);
  k_fill        <<<ceil_div(E,256),256,0,stream>>>(src, dst, cursor,
                                                   csr_src, csr_dst, csr_eid, E);

  // --- layer 1: t1 = x@W1 ---
  k_gemm<128,64><<<ceil_div(N,4),256,0,stream>>>(x, W1, t1, N);
  // --- agg1 + fused (h1@W2): t2 ---
  k_agg_fused<1><<<ceil_div(N,4),256,0,stream>>>(t1, csr_src, row_start, cnt,
                                                 dinv, b1, W2, t2, N);
  // --- agg2 + fused (h2@Wm1): AB ---
  k_agg_fused<2><<<ceil_div(N,4),256,0,stream>>>(t2, csr_src, row_start, cnt,
                                                 dinv, b2, Wm1, AB, N);
  // --- edge MLP ---
  k_edge_mlp<<<ceil_div(E,256),256,0,stream>>>(csr_src, csr_dst, csr_eid, AB,
                                               bm1, Wm2, bm2, out, E);
}

// Round 7
// 405.025 us; speedup vs baseline: 1.5165x; 1.0084x over previous
//
#include <hip/hip_runtime.h>
#include <hip/hip_bf16.h>

// GCN (2-layer, PyG-style symmetric norm + self loops) + edge MLP.
//  - CSR by dst (hist -> 3-level scan -> fill). No fp32 atomics.
//  - gcn_conv: t' = (h@W) * dinv[row] (producer-side scale), then per-node:
//      out[v] = relu(dinv[v]*( t'[v] + sum_{(s,v)} t'[s] ) + b)
//    -> gather loop needs NO per-edge weight (dinv folded into the table).
//  - Edge MLP: ef@Wm1 = A[src]+B[dst], A/B precomputed per node.
// R2: 3-level scan replaces single-block scan (was 111us @ 0.14% occ).
// R3: k_edge_mlp in CSR(dst) order -> B[d] wave-broadcast; 107->63.6us.
// R4: per-node GEMMs fused into k_agg epilogue.
// R5: coop batch index load + readlane broadcast (82->72us).
// R6: dinv folded into producer rows (kills the chained dinv gather + per-edge
//     weight readlane); 8 gathers in flight; epilogue via readlane broadcast
//     (no LDS, no __syncthreads -> waves decoupled).

#define HDIM 64
#define CDIM 16

static inline int ceil_div(int a, int b){ return (a+b-1)/b; }

__device__ inline float readlane_f(float v, int l){
  return __uint_as_float(__builtin_amdgcn_readlane(__float_as_uint(v), l));
}

__global__ void k_zero_i32(int* p, int n){
  int i = blockIdx.x*blockDim.x + threadIdx.x;
  if(i<n) p[i]=0;
}

__global__ void k_hist(const int* __restrict__ dst, int* __restrict__ cnt, int E){
  int e = blockIdx.x*blockDim.x + threadIdx.x;
  if(e<E) atomicAdd(&cnt[dst[e]], 1);
}

// Level 1: per-block (256 nodes) sum of cnt -> bsum[block]
__global__ __launch_bounds__(256) void k_blocksum(const int* __restrict__ cnt,
                                                  int* __restrict__ bsum, int N){
  __shared__ int part[4];
  int i = blockIdx.x*256 + threadIdx.x;
  int v = (i<N) ? cnt[i] : 0;
  #pragma unroll
  for(int off=32; off>0; off>>=1) v += __shfl_down(v, off, 64);
  if((threadIdx.x & 63)==0) part[threadIdx.x>>6] = v;
  __syncthreads();
  if(threadIdx.x==0) bsum[blockIdx.x] = part[0]+part[1]+part[2]+part[3];
}

// Level 2: one block scans the per-block sums (nb <= 1024) -> exclusive prefix.
__global__ __launch_bounds__(1024) void k_scan_bsums(int* __restrict__ bsum, int nb){
  __shared__ int tmp[1024];
  int tid = threadIdx.x;
  int v = (tid<nb) ? bsum[tid] : 0;
  tmp[tid] = v; __syncthreads();
  for(int off=1; off<1024; off<<=1){
    int add = (tid>=off) ? tmp[tid-off] : 0;
    __syncthreads();
    tmp[tid] += add;
    __syncthreads();
  }
  if(tid<nb) bsum[tid] = tmp[tid] - v;   // exclusive
}

// Level 3: in-block exclusive scan of cnt + block offset -> row_start/cursor.
// Also computes dinv (needs only cnt).
__global__ __launch_bounds__(256) void k_write_prefix(const int* __restrict__ cnt,
                                                      const int* __restrict__ bsum,
                                                      int* __restrict__ row_start,
                                                      int* __restrict__ cursor,
                                                      float* __restrict__ dinv, int N){
  __shared__ int tmp[256];
  int tid = threadIdx.x;
  int i = blockIdx.x*256 + tid;
  int v = (i<N) ? cnt[i] : 0;
  tmp[tid] = v; __syncthreads();
  for(int off=1; off<256; off<<=1){
    int add = (tid>=off) ? tmp[tid-off] : 0;
    __syncthreads();
    tmp[tid] += add;
    __syncthreads();
  }
  if(i<N){
    int ex = bsum[blockIdx.x] + tmp[tid] - v;
    row_start[i] = ex;
    cursor[i]    = ex;
    dinv[i]      = 1.0f / sqrtf(1.0f + (float)v);  // deg >= 1 via self-loop
  }
}

__global__ void k_fill(const int* __restrict__ src, const int* __restrict__ dst,
                       int* __restrict__ cursor,
                       int* __restrict__ csr_src, int* __restrict__ csr_dst,
                       int* __restrict__ csr_eid, int E){
  int e = blockIdx.x*blockDim.x + threadIdx.x;
  if(e>=E) return;
  int s = src[e], d = dst[e];
  int pos = atomicAdd(&cursor[d], 1);
  csr_src[pos] = s;
  csr_dst[pos] = d;
  csr_eid[pos] = e;
}

// out[n][c] = (sum_k in[n][k] * W[k][c]) * dscale[n]; one block = 4 nodes,
// input rows staged in LDS, W coalesced + L1-resident. dscale[n] is
// wave-uniform (y = wave id) -> s_load.
template<int K, int COLS>
__global__ __launch_bounds__(256) void k_gemm(const float* __restrict__ in,
                                              const float* __restrict__ W,
                                              const float* __restrict__ dscale,
                                              float* __restrict__ out, int N){
  const int NODES = 256/COLS;
  __shared__ float srow[NODES*K];
  int n0 = blockIdx.x*NODES;
  for(int i=threadIdx.x; i<NODES*K; i+=256){
    int g = n0*K + i;
    srow[i] = (g < N*K) ? in[g] : 0.f;
  }
  __syncthreads();
  int c = threadIdx.x % COLS;
  int y = threadIdx.x / COLS;
  int n = n0+y;
  if(n>=N) return;
  float acc=0.f;
  #pragma unroll
  for(int k=0;k<K;k++) acc += srow[y*K+k]*W[k*COLS+c];
  out[n*COLS+c]=acc*dscale[n];
}

// Fused: gather-aggregate over pre-scaled table t' -> r = relu(acc*dv + b)
// -> per-node GEMM epilogue vs Wepi (GROUPS*64 x 64 row-major) via readlane
// broadcast (no LDS, no barrier). SCALE_OUT: store s_out*dv (produce next t').
// Gather: coop batch load of <=64 src indices (1 coalesced load), readlane
// broadcast, 8 independent 256B row gathers in flight, pure adds.
template<int GROUPS, bool SCALE_OUT>
__global__ __launch_bounds__(256) void k_agg_fused(const float* __restrict__ t,
                                                   const int* __restrict__ csr_src,
                                                   const int* __restrict__ row_start,
                                                   const int* __restrict__ cnt,
                                                   const float* __restrict__ dinv,
                                                   const float* __restrict__ bias,
                                                   const float* __restrict__ Wepi,
                                                   float* __restrict__ outbuf, int N){
  int lane = threadIdx.x & 63;
  int w    = threadIdx.x >> 6;
  int v    = blockIdx.x*4 + w;
  bool act = (v < N);
  int vv   = act ? v : 0;

  float dv = dinv[vv];
  float a0 = t[(size_t)vv*HDIM + lane];   // self term (t' already has dinv[v])
  float a1=0.f,a2=0.f,a3=0.f,a4=0.f,a5=0.f,a6=0.f,a7=0.f;
  int j0  = act ? row_start[vv] : 0;
  int deg = act ? cnt[vv] : 0;

  for(int b=0; b<deg; b+=64){
    int m = deg - b; if(m>64) m=64;
    int idxv = 0;
    if(lane < m) idxv = csr_src[j0 + b + lane];  // one coalesced load per batch
    int k=0;
    for(; k+7<m; k+=8){
      int s0 = __builtin_amdgcn_readlane(idxv, k);
      int s1 = __builtin_amdgcn_readlane(idxv, k+1);
      int s2 = __builtin_amdgcn_readlane(idxv, k+2);
      int s3 = __builtin_amdgcn_readlane(idxv, k+3);
      int s4 = __builtin_amdgcn_readlane(idxv, k+4);
      int s5 = __builtin_amdgcn_readlane(idxv, k+5);
      int s6 = __builtin_amdgcn_readlane(idxv, k+6);
      int s7 = __builtin_amdgcn_readlane(idxv, k+7);
      a0 += t[(size_t)s0*HDIM+lane];
      a1 += t[(size_t)s1*HDIM+lane];
      a2 += t[(size_t)s2*HDIM+lane];
      a3 += t[(size_t)s3*HDIM+lane];
      a4 += t[(size_t)s4*HDIM+lane];
      a5 += t[(size_t)s5*HDIM+lane];
      a6 += t[(size_t)s6*HDIM+lane];
      a7 += t[(size_t)s7*HDIM+lane];
    }
    for(; k<m; k++){
      int s = __builtin_amdgcn_readlane(idxv, k);
      a0 += t[(size_t)s*HDIM+lane];
    }
  }
  float acc = ((a0+a1)+(a2+a3)) + ((a4+a5)+(a6+a7));
  float r = acc*dv + bias[lane];
  r = r>0.f ? r : 0.f;                 // h-row value for feature `lane`

  float s_out[GROUPS];
  #pragma unroll
  for(int g=0; g<GROUPS; g++) s_out[g] = 0.f;
  #pragma unroll
  for(int k=0; k<HDIM; k++){
    float hv = readlane_f(r, k);       // wave-broadcast of feature k
    #pragma unroll
    for(int g=0; g<GROUPS; g++)
      s_out[g] += hv * Wepi[(size_t)(g*HDIM + k)*HDIM + lane];  // coalesced, L1-hit
  }
  if(act){
    #pragma unroll
    for(int g=0; g<GROUPS; g++){
      float o = SCALE_OUT ? s_out[g]*dv : s_out[g];
      outbuf[(size_t)v*(GROUPS*HDIM) + g*HDIM + lane] = o;
    }
  }
}

// Edge MLP in CSR(dst) order: thread j -> (s, d, eid). Consecutive threads share
// d -> B[d] reads broadcast/stream. A[s] random: 16 float4 loads in flight.
__global__ __launch_bounds__(256) void k_edge_mlp(const int* __restrict__ csr_src,
                                                  const int* __restrict__ csr_dst,
                                                  const int* __restrict__ csr_eid,
                                                  const float* __restrict__ AB,
                                                  const float* __restrict__ bm1,
                                                  const float* __restrict__ Wm2,
                                                  const float* __restrict__ bm2,
                                                  float* __restrict__ out, int E){
  int j = blockIdx.x*blockDim.x + threadIdx.x;
  if(j>=E) return;
  int s = csr_src[j], d = csr_dst[j], eid = csr_eid[j];
  const float4* Af = (const float4*)(AB + (size_t)s*128);
  const float4* Bf = (const float4*)(AB + (size_t)d*128 + 64);
  const float4* bm1f = (const float4*)bm1;
  const float4* bm2f = (const float4*)bm2;

  float4 a[16];
  #pragma unroll
  for(int k0=0;k0<16;k0++) a[k0] = Af[k0];   // random-side gather, 16 in flight

  float acc[CDIM];
  {
    float4 c0 = bm2f[0], c1 = bm2f[1], c2 = bm2f[2], c3 = bm2f[3];
    acc[0]=c0.x; acc[1]=c0.y; acc[2]=c0.z; acc[3]=c0.w;
    acc[4]=c1.x; acc[5]=c1.y; acc[6]=c1.z; acc[7]=c1.w;
    acc[8]=c2.x; acc[9]=c2.y; acc[10]=c2.z; acc[11]=c2.w;
    acc[12]=c3.x; acc[13]=c3.y; acc[14]=c3.z; acc[15]=c3.w;
  }
  #pragma unroll
  for(int k0=0;k0<16;k0++){
    float4 b  = Bf[k0];     // same d across wave -> broadcast / L1-hit
    float4 bb = bm1f[k0];   // wave-uniform -> s_load
    float z0 = a[k0].x+b.x+bb.x; z0 = z0>0.f? z0:0.f;
    float z1 = a[k0].y+b.y+bb.y; z1 = z1>0.f? z1:0.f;
    float z2 = a[k0].z+b.z+bb.z; z2 = z2>0.f? z2:0.f;
    float z3 = a[k0].w+b.w+bb.w; z3 = z3>0.f? z3:0.f;
    #pragma unroll
    for(int c=0;c<CDIM;c++){
      acc[c] += z0 * Wm2[(k0*4+0)*CDIM + c];
      acc[c] += z1 * Wm2[(k0*4+1)*CDIM + c];
      acc[c] += z2 * Wm2[(k0*4+2)*CDIM + c];
      acc[c] += z3 * Wm2[(k0*4+3)*CDIM + c];
    }
  }
  float4* o = (float4*)(out + (size_t)eid*CDIM);
  o[0] = make_float4(acc[0],acc[1],acc[2],acc[3]);
  o[1] = make_float4(acc[4],acc[5],acc[6],acc[7]);
  o[2] = make_float4(acc[8],acc[9],acc[10],acc[11]);
  o[3] = make_float4(acc[12],acc[13],acc[14],acc[15]);
}

extern "C" void kernel_launch(void* const* d_in, const int* in_sizes, int n_in,
                              void* d_out, int out_size, void* d_ws, size_t ws_size,
                              hipStream_t stream) {
  const float* x   = (const float*)d_in[0];
  const int*   ei  = (const int*)  d_in[1];
  const float* W1  = (const float*)d_in[2];
  const float* b1  = (const float*)d_in[3];
  const float* W2  = (const float*)d_in[4];
  const float* b2  = (const float*)d_in[5];
  const float* Wm1 = (const float*)d_in[6];
  const float* bm1 = (const float*)d_in[7];
  const float* Wm2 = (const float*)d_in[8];
  const float* bm2 = (const float*)d_in[9];
  float* out = (float*)d_out;

  const int N = in_sizes[0]/128;
  const int E = in_sizes[1]/2;
  const int* src = ei;
  const int* dst = ei + E;

  const int NB = ceil_div(N,256);

  // ws layout (256B-aligned). t1 (N*64) aliases AB's low half: t1 is dead
  // (last read by aggF<1>) before aggF<2> writes AB.
  char* ws = (char*)d_ws;
  size_t off = 0;
  auto alloc = [&](size_t bytes)->char*{
    char* p = ws + off; off += (bytes + 255) & ~(size_t)255; return p;
  };
  int*   cnt       = (int*)  alloc((size_t)N*4);
  int*   row_start = (int*)  alloc((size_t)N*4);
  int*   cursor    = (int*)  alloc((size_t)N*4);
  float* dinv      = (float*)alloc((size_t)N*4);
  int*   bsum      = (int*)  alloc((size_t)NB*4);
  int*   csr_src   = (int*)  alloc((size_t)E*4);
  int*   csr_dst   = (int*)  alloc((size_t)E*4);
  int*   csr_eid   = (int*)  alloc((size_t)E*4);
  float* AB        = (float*)alloc((size_t)N*128*4);
  float* t1        = AB;                               // alias: low 12.8MB of AB
  float* t2        = (float*)alloc((size_t)N*64*4);

  // --- CSR build ---
  k_zero_i32    <<<ceil_div(N,256),256,0,stream>>>(cnt, N);
  k_hist        <<<ceil_div(E,256),256,0,stream>>>(dst, cnt, E);
  k_blocksum    <<<NB,256,0,stream>>>(cnt, bsum, N);
  k_scan_bsums  <<<1,1024,0,stream>>>(bsum, NB);
  k_write_prefix<<<NB,256,0,stream>>>(cnt, bsum, row_start, cursor, dinv, N);
  k_fill        <<<ceil_div(E,256),256,0,stream>>>(src, dst, cursor,
                                                   csr_src, csr_dst, csr_eid, E);

  // --- layer 1: t1' = (x@W1)*dinv ---
  k_gemm<128,64><<<ceil_div(N,4),256,0,stream>>>(x, W1, dinv, t1, N);
  // --- agg1 + fused (h1@W2), output pre-scaled: t2' ---
  k_agg_fused<1,true ><<<ceil_div(N,4),256,0,stream>>>(t1, csr_src, row_start, cnt,
                                                       dinv, b1, W2, t2, N);
  // --- agg2 + fused (h2@Wm1): AB (unscaled) ---
  k_agg_fused<2,false><<<ceil_div(N,4),256,0,stream>>>(t2, csr_src, row_start, cnt,
                                                       dinv, b2, Wm1, AB, N);
  // --- edge MLP ---
  k_edge_mlp<<<ceil_div(E,256),256,0,stream>>>(csr_src, csr_dst, csr_eid, AB,
                                               bm1, Wm2, bm2, out, E);
}